// Round 1
// baseline (87.944 us; speedup 1.0000x reference)
//
#include <hip/hip_runtime.h>
#include <math.h>

// Problem constants (from reference setup_inputs)
constexpr int Bn = 4, Tn = 1000, Fn = 257, Cn = 6, Dn = 2048, On = 2;
constexpr int BTn = Bn * Tn;                      // 4000
constexpr double DEG2RAD = 0.017453292519943295;  // pi/180 in double

// Output segment offsets (in floats) within d_out
constexpr size_t OUT0_F = (size_t)BTn * Fn * Cn * 2;  // 12,336,000
constexpr size_t OUT1_F = (size_t)BTn * Fn * 2;       //  2,056,000
// out2 = BTn*Fn*On*2 = 4,112,000

// Workspace layout (bytes)
constexpr size_t TAB_BYTES  = (size_t)5 * Dn * sizeof(double);              // 81,920 (SoA [5][D])
constexpr size_t WTC_BYTES  = (size_t)Dn * Fn * Cn * 2 * sizeof(float);     // 25,264,128
constexpr size_t WTB_BYTES  = (size_t)Dn * Fn * On * 2 * sizeof(float);     //  8,421,376
constexpr size_t WS_NEEDED  = TAB_BYTES + 2 * WTC_BYTES + WTB_BYTES;        // ~56.3 MiB

// ---------------------------------------------------------------------------
// K0: per-direction trig table in double (SoA: tab[j*Dn + d])
//   j=0: sin(d0/2)  j=1: cos(d0/2)  j=2: sin(d1/2)  j=3: cos(d1/2)  j=4: cos(d1)
// ---------------------------------------------------------------------------
__global__ __launch_bounds__(256) void build_dir_table(const float2* __restrict__ dirs,
                                                       double* __restrict__ tab) {
    int d = blockIdx.x * blockDim.x + threadIdx.x;
    if (d >= Dn) return;
    float2 dr = dirs[d];
    double d0 = (double)dr.x, d1 = (double)dr.y;
    tab[0 * Dn + d] = sin(0.5 * d0);
    tab[1 * Dn + d] = cos(0.5 * d0);
    tab[2 * Dn + d] = sin(0.5 * d1);
    tab[3 * Dn + d] = cos(0.5 * d1);
    tab[4 * Dn + d] = cos(d1);
}

// ---------------------------------------------------------------------------
// K1: transpose a (real,imag) pair  src[CC,Fn,Dn] -> dst float2 [Dn][Fn][CC]
//   dst[(d*Fn + f)*CC + c] = {src_r[(c*Fn+f)*Dn + d], src_i[...]}
// Tiled: 48 rows (FB f-values x CC channels) x 64 d per block, LDS 48x65 float2.
// ---------------------------------------------------------------------------
template <int CC>
__global__ __launch_bounds__(256) void transpose_w(const float* __restrict__ wr,
                                                   const float* __restrict__ wi,
                                                   float2* __restrict__ dst) {
    constexpr int ROWS = 48;
    constexpr int FB = ROWS / CC;
    __shared__ float2 tile[ROWS][65];
    const int d0 = blockIdx.x * 64;
    const int f0 = blockIdx.y * FB;
    const int tid = threadIdx.x;

    #pragma unroll
    for (int j = 0; j < (ROWS * 64) / 256; ++j) {
        int idx = j * 256 + tid;
        int r2 = idx >> 6;       // row in dst order: r2 = fi*CC + c
        int dl = idx & 63;
        int fi = r2 / CC, c = r2 % CC;
        int f = f0 + fi;
        if (f < Fn) {
            size_t s = (size_t)(c * Fn + f) * Dn + (size_t)(d0 + dl);
            tile[r2][dl] = make_float2(wr[s], wi[s]);
        }
    }
    __syncthreads();
    #pragma unroll
    for (int j = 0; j < (ROWS * 64) / 256; ++j) {
        int idx = j * 256 + tid;
        int dl = idx / ROWS;
        int r2 = idx % ROWS;
        int f = f0 + r2 / CC;
        if (f < Fn) {
            size_t o = (size_t)(d0 + dl) * Fn * CC + (size_t)f0 * CC + (size_t)r2;
            dst[o] = tile[r2][dl];
        }
    }
}

// ---------------------------------------------------------------------------
// Block-wide argmin reduction helper data is inlined in kernels below.
// ---------------------------------------------------------------------------

// K2: fused argmin + gather/multiply, fast path (transposed weights)
__global__ __launch_bounds__(256) void main_fast(
    const float* __restrict__ Xr, const float* __restrict__ Xi,
    const float* __restrict__ tdoa, const double* __restrict__ tab,
    const float* __restrict__ wTc, const float* __restrict__ wTd,
    const float* __restrict__ wTb,
    float2* __restrict__ out0, float2* __restrict__ out1, float4* __restrict__ out2) {
    const int bt = blockIdx.x;
    const int tid = threadIdx.x;
    __shared__ double sv[256];
    __shared__ int si[256];

    // ---- argmin over direction codebook (float64 for index fidelity) ----
    double t0 = DEG2RAD * (double)tdoa[bt * 2 + 0];
    double t1 = DEG2RAD * (double)tdoa[bt * 2 + 1];
    double st0h = sin(0.5 * t0), ct0h = cos(0.5 * t0);
    double st1h = sin(0.5 * t1), ct1h = cos(0.5 * t1);
    double ct1 = cos(t1);
    double best = 1e300;
    int bidx = 0;
    for (int d = tid; d < Dn; d += 256) {
        // sin((t-d)/2) = sin(t/2)cos(d/2) - cos(t/2)sin(d/2)
        double s1 = st1h * tab[3 * Dn + d] - ct1h * tab[2 * Dn + d];
        double s2 = st0h * tab[1 * Dn + d] - ct0h * tab[0 * Dn + d];
        double a = s1 * s1 + ct1 * tab[4 * Dn + d] * (s2 * s2);
        if (a < best) { best = a; bidx = d; }  // ascending d per thread -> first-min kept
    }
    sv[tid] = best; si[tid] = bidx;
    __syncthreads();
    for (int s = 128; s > 0; s >>= 1) {
        if (tid < s) {
            double v = sv[tid + s]; int j = si[tid + s];
            if (v < sv[tid] || (v == sv[tid] && j < si[tid])) { sv[tid] = v; si[tid] = j; }
        }
        __syncthreads();
    }
    const int dsel = si[0];

    // ---- gather + complex multiply, fully coalesced ----
    const float4* wc4 = (const float4*)(wTc + (size_t)dsel * Fn * Cn * 2);  // [Fn*Cn] complex
    const float4* wd4 = (const float4*)(wTd + (size_t)dsel * Fn * Cn * 2);
    const float4* wb4 = (const float4*)(wTb + (size_t)dsel * Fn * On * 2);  // [Fn] float4 (2 complex)
    const size_t base = (size_t)bt * Fn * Cn;  // complex-element base for X / out0

    for (int f = tid; f < Fn; f += 256) {
        const int fc = f * Cn;
        // load 6 complex X values via float2 (8B-aligned)
        float xr[Cn], xi[Cn];
        const float2* xr2 = (const float2*)(Xr + base + fc);
        const float2* xi2 = (const float2*)(Xi + base + fc);
        #pragma unroll
        for (int k = 0; k < Cn / 2; ++k) {
            float2 a = xr2[k]; xr[2 * k] = a.x; xr[2 * k + 1] = a.y;
            float2 b = xi2[k]; xi[2 * k] = b.x; xi[2 * k + 1] = b.y;
        }
        float4* o0 = (float4*)(out0 + base + fc);  // 16B-aligned: base+fc elements *8B
        float accr = 0.f, acci = 0.f;
        #pragma unroll
        for (int k = 0; k < Cn / 2; ++k) {  // two complex per float4
            float4 wdv = wd4[f * 3 + k];
            float4 wcv = wc4[f * 3 + k];
            int c0 = 2 * k, c1 = 2 * k + 1;
            float4 r;
            r.x = wdv.x * xr[c0] - wdv.y * xi[c0];
            r.y = wdv.x * xi[c0] + wdv.y * xr[c0];
            r.z = wdv.z * xr[c1] - wdv.w * xi[c1];
            r.w = wdv.z * xi[c1] + wdv.w * xr[c1];
            o0[k] = r;
            accr += wcv.x * xr[c0] - wcv.y * xi[c0];
            acci += wcv.x * xi[c0] + wcv.y * xr[c0];
            accr += wcv.z * xr[c1] - wcv.w * xi[c1];
            acci += wcv.z * xi[c1] + wcv.w * xr[c1];
        }
        out1[(size_t)bt * Fn + f] = make_float2(accr, acci);
        out2[(size_t)bt * Fn + f] = wb4[f];  // both O channels, bit-exact copy
    }
}

// K2': fallback (no workspace): direct strided gather, per-point double trig
__global__ __launch_bounds__(256) void main_direct(
    const float* __restrict__ Xr, const float* __restrict__ Xi,
    const float* __restrict__ tdoa, const float2* __restrict__ dirs,
    const float* __restrict__ wcr, const float* __restrict__ wci,
    const float* __restrict__ wdr, const float* __restrict__ wdi,
    const float* __restrict__ wbr, const float* __restrict__ wbi,
    float2* __restrict__ out0, float2* __restrict__ out1, float2* __restrict__ out2) {
    const int bt = blockIdx.x;
    const int tid = threadIdx.x;
    __shared__ double sv[256];
    __shared__ int si[256];

    double t0 = DEG2RAD * (double)tdoa[bt * 2 + 0];
    double t1 = DEG2RAD * (double)tdoa[bt * 2 + 1];
    double ct1 = cos(t1);
    double best = 1e300;
    int bidx = 0;
    for (int d = tid; d < Dn; d += 256) {
        float2 dr = dirs[d];
        double s1 = sin(0.5 * (t1 - (double)dr.y));
        double s2 = sin(0.5 * (t0 - (double)dr.x));
        double a = s1 * s1 + ct1 * cos((double)dr.y) * (s2 * s2);
        if (a < best) { best = a; bidx = d; }
    }
    sv[tid] = best; si[tid] = bidx;
    __syncthreads();
    for (int s = 128; s > 0; s >>= 1) {
        if (tid < s) {
            double v = sv[tid + s]; int j = si[tid + s];
            if (v < sv[tid] || (v == sv[tid] && j < si[tid])) { sv[tid] = v; si[tid] = j; }
        }
        __syncthreads();
    }
    const int dsel = si[0];
    const size_t base = (size_t)bt * Fn * Cn;

    for (int f = tid; f < Fn; f += 256) {
        const int fc = f * Cn;
        float accr = 0.f, acci = 0.f;
        #pragma unroll
        for (int c = 0; c < Cn; ++c) {
            float xr = Xr[base + fc + c], xi = Xi[base + fc + c];
            size_t wo = (size_t)(c * Fn + f) * Dn + dsel;
            float a_ = wdr[wo], b_ = wdi[wo];
            out0[base + fc + c] = make_float2(a_ * xr - b_ * xi, a_ * xi + b_ * xr);
            float p = wcr[wo], q = wci[wo];
            accr += p * xr - q * xi;
            acci += p * xi + q * xr;
        }
        out1[(size_t)bt * Fn + f] = make_float2(accr, acci);
        #pragma unroll
        for (int o = 0; o < On; ++o) {
            size_t wo = (size_t)(o * Fn + f) * Dn + dsel;
            out2[((size_t)bt * Fn + f) * On + o] = make_float2(wbr[wo], wbi[wo]);
        }
    }
}

extern "C" void kernel_launch(void* const* d_in, const int* in_sizes, int n_in,
                              void* d_out, int out_size, void* d_ws, size_t ws_size,
                              hipStream_t stream) {
    const float* Xr   = (const float*)d_in[0];
    const float* Xi   = (const float*)d_in[1];
    const float* tdoa = (const float*)d_in[2];
    const float2* dirs = (const float2*)d_in[3];
    const float* wcr = (const float*)d_in[4];
    const float* wci = (const float*)d_in[5];
    const float* wdr = (const float*)d_in[6];
    const float* wdi = (const float*)d_in[7];
    const float* wbr = (const float*)d_in[8];
    const float* wbi = (const float*)d_in[9];

    float* out = (float*)d_out;
    float2* out0 = (float2*)out;
    float2* out1 = (float2*)(out + OUT0_F);
    float2* out2f2 = (float2*)(out + OUT0_F + OUT1_F);
    float4* out2 = (float4*)(out + OUT0_F + OUT1_F);

    if (ws_size >= WS_NEEDED) {
        char* ws = (char*)d_ws;
        double* tab = (double*)ws;
        float* wTc = (float*)(ws + TAB_BYTES);
        float* wTd = (float*)(ws + TAB_BYTES + WTC_BYTES);
        float* wTb = (float*)(ws + TAB_BYTES + 2 * WTC_BYTES);

        build_dir_table<<<Dn / 256, 256, 0, stream>>>(dirs, tab);
        dim3 g6(Dn / 64, (Fn + 7) / 8);     // 32 x 33
        dim3 g2(Dn / 64, (Fn + 23) / 24);   // 32 x 11
        transpose_w<6><<<g6, 256, 0, stream>>>(wcr, wci, (float2*)wTc);
        transpose_w<6><<<g6, 256, 0, stream>>>(wdr, wdi, (float2*)wTd);
        transpose_w<2><<<g2, 256, 0, stream>>>(wbr, wbi, (float2*)wTb);
        main_fast<<<BTn, 256, 0, stream>>>(Xr, Xi, tdoa, tab, wTc, wTd, wTb,
                                           out0, out1, out2);
    } else {
        main_direct<<<BTn, 256, 0, stream>>>(Xr, Xi, tdoa, dirs,
                                             wcr, wci, wdr, wdi, wbr, wbi,
                                             out0, out1, out2f2);
    }
}